// Round 4
// baseline (5025.876 us; speedup 1.0000x reference)
//
#include <hip/hip_runtime.h>

#define B_ 1024
#define L_ 80
#define E_ 256
#define D_ 256
#define T_ 20
#define NS_ 4
#define NSYM_ 100

#define ROWS 16      // batch rows per decode block
#define NBLK 64      // B_ / ROWS
#define XP 520       // padded LDS row stride (shorts) for [16][512] X buffers
#define WSP 520      // padded LDS row stride (shorts) for weight chunk
#define WAP 264      // padded LDS row stride (shorts) for WaH

typedef __attribute__((ext_vector_type(8))) short short8;
typedef __attribute__((ext_vector_type(4))) float f32x4;

__device__ inline short f2b(float f) {
    unsigned u = __float_as_uint(f);
    unsigned r = (u + 0x7fffu + ((u >> 16) & 1u)) >> 16;
    return (short)r;
}
__device__ inline float b2f(short s) {
    return __uint_as_float(((unsigned)(unsigned short)s) << 16);
}

// ---------------- init / conversion kernels ----------------

__global__ void f2b4_k(const float* __restrict__ src, short* __restrict__ dst, size_t n4) {
    size_t i = (size_t)blockIdx.x * blockDim.x + threadIdx.x;
    size_t stride = (size_t)gridDim.x * blockDim.x;
    for (; i < n4; i += stride) {
        float4 v = ((const float4*)src)[i];
        short4 o;
        o.x = f2b(v.x); o.y = f2b(v.y); o.z = f2b(v.z); o.w = f2b(v.w);
        ((short4*)dst)[i] = o;
    }
}

// split W [rows, 512] into two bf16 [rows, 256] halves
__global__ void split_k(const float* __restrict__ Wsrc, short* __restrict__ dstE,
                        short* __restrict__ dstH, int rows) {
    int id = blockIdx.x * 256 + threadIdx.x;
    if (id >= rows * 512) return;
    int rr = id >> 9, cc = id & 511;
    short v = f2b(Wsrc[id]);
    if (cc < 256) dstE[rr * 256 + cc] = v;
    else          dstH[rr * 256 + (cc - 256)] = v;
}

// build gate-interleaved [1024, 512] bf16 weights: row (4u+g) = [Wih[g*256+u,:] | Whh[g*256+u,:]]
__global__ void gatesW_k(const float* __restrict__ Wih, const float* __restrict__ Whh,
                         const float* __restrict__ bih, const float* __restrict__ bhh,
                         short* __restrict__ WgB, float* __restrict__ bg) {
    int id = blockIdx.x * 256 + threadIdx.x;   // < 524288
    int np = id >> 9, cc = id & 511;
    int u = np >> 2, g = np & 3;
    int srow = g * 256 + u;
    float v = (cc < 256) ? Wih[srow * 256 + cc] : Whh[srow * 256 + (cc - 256)];
    WgB[id] = f2b(v);
    if (id < 1024) {
        int u2 = id >> 2, g2 = id & 3;
        bg[id] = bih[g2 * 256 + u2] + bhh[g2 * 256 + u2];
    }
}

// embedding gather -> bf16 embB [T*B, D] with row r = t*B + b
__global__ void embed_k(const int* __restrict__ tsi, const float* __restrict__ common,
                        const float* __restrict__ syms, short* __restrict__ embB) {
    size_t id = (size_t)blockIdx.x * 256 + threadIdx.x;  // < T*B*D
    int d = (int)(id & 255);
    size_t r = id >> 8;
    int tt = (int)(r >> 10);      // B_ = 1024
    int b  = (int)(r & 1023);
    int idx = tsi[b * T_ + tt];
    float v;
    if (idx < NS_) {
        int i2 = idx < 0 ? 0 : idx;
        v = common[i2 * D_ + d];
    } else {
        int i2 = idx - NS_;
        if (i2 > NSYM_ - 1) i2 = NSYM_ - 1;
        v = syms[((size_t)b * NSYM_ + i2) * D_ + d];
    }
    embB[id] = f2b(v);
}

// ---------------- generic bf16 MFMA GEMM: C = act(A @ W^T + addend + bias) ----------------

__global__ __launch_bounds__(256) void gemm_k(
    const short* __restrict__ A, int lda,
    const short* __restrict__ W,
    const float* __restrict__ addend, int ldAdd,
    const float* __restrict__ bias,
    int act,
    float* __restrict__ outF, int ldoF,
    short* __restrict__ outB, int ldoB,
    int M, int N, int K)
{
    __shared__ alignas(16) short As[64][40];
    __shared__ alignas(16) short Ws[64][40];
    int m0 = blockIdx.x * 64, n0 = blockIdx.y * 64;
    int t = threadIdx.x;
    int w = t >> 6, l = t & 63, quad = l >> 4, lm = l & 15;
    int wm = (w >> 1) * 32, wn = (w & 1) * 32;
    f32x4 acc[2][2] = {};
    int rowL = t >> 2, c8 = (t & 3) * 8;
    for (int k0 = 0; k0 < K; k0 += 32) {
        uint4 av = *(const uint4*)(A + (size_t)(m0 + rowL) * lda + k0 + c8);
        uint4 wv = {0u, 0u, 0u, 0u};
        int wr = n0 + rowL;
        if (wr < N) wv = *(const uint4*)(W + (size_t)wr * K + k0 + c8);
        *(uint4*)&As[rowL][c8] = av;
        *(uint4*)&Ws[rowL][c8] = wv;
        __syncthreads();
        short8 af[2], wf[2];
        af[0] = *(const short8*)&As[wm + lm][quad * 8];
        af[1] = *(const short8*)&As[wm + 16 + lm][quad * 8];
        wf[0] = *(const short8*)&Ws[wn + lm][quad * 8];
        wf[1] = *(const short8*)&Ws[wn + 16 + lm][quad * 8];
        #pragma unroll
        for (int i = 0; i < 2; i++)
            #pragma unroll
            for (int j = 0; j < 2; j++)
                acc[i][j] = __builtin_amdgcn_mfma_f32_16x16x32_bf16(af[i], wf[j], acc[i][j], 0, 0, 0);
        __syncthreads();
    }
    #pragma unroll
    for (int i = 0; i < 2; i++)
        #pragma unroll
        for (int j = 0; j < 2; j++) {
            int col = n0 + wn + j * 16 + lm;
            if (col >= N) continue;
            float bval = bias ? bias[col] : 0.f;
            #pragma unroll
            for (int r = 0; r < 4; r++) {
                int row = m0 + wm + i * 16 + quad * 4 + r;
                float v = acc[i][j][r] + bval;
                if (addend) v += addend[(size_t)row * ldAdd + col];
                if (act == 1) v = fmaxf(v, 0.f);
                if (outF) outF[(size_t)row * ldoF + col] = v;
                if (outB) outB[(size_t)row * ldoB + col] = f2b(v);
            }
        }
}

// ---------------- batch-local persistent decode ----------------
// 64 blocks x 16 batch rows; all T steps in-kernel. Weights staged through LDS
// in 64-gate chunks (block-cooperative coalesced loads -> no per-wave latency chains).

struct DecArgs {
    short* H1all;        // [T*B, 256] bf16; slot tt = h1 after step tt
    const short* WaHB;   // [80, 256] bf16
    const float* awE;    // [T*B, 80]  (includes b_attn)
    const short* encW;   // [B, 80, 256] bf16 = enc @ WcA^T
    const float* combE;  // [T*B, 256] (includes b_comb)
    const short* Wg0; const float* bg0;
    const short* Wg1; const float* bg1;
};

struct DecShared {
    alignas(16) short X0[ROWS][XP];       // [comb | h0_prev]
    alignas(16) short X1[ROWS][XP];       // [h0   | h1_prev]
    alignas(16) short Ws[64][WSP];        // staged weight chunk (64 gate rows x 512)
    alignas(16) short WaHs[80][WAP];      // staged attention weights (whole kernel)
    float awS[ROWS][80];
    float apS[ROWS][80];
    alignas(16) float gSv[4][ROWS][20];   // per-wave 4x4-transpose staging
};

// gates GEMM (16 x 1024, K=512) + LSTM for this block's 16 rows, LDS-staged weights.
__device__ inline void layer_lstm(
    DecShared& s,
    const short (*X)[XP],            // [16][512] bf16 input = [x | h_prev] (LDS)
    const short* __restrict__ Wg,    // [1024][512] bf16 gate-interleaved (global)
    const float* __restrict__ bg,    // [1024]
    float* creg,                     // [16] per-lane cell state
    short (*D1)[XP], int o1,         // LDS h dest 1
    short (*D2)[XP], int o2,         // LDS h dest 2 (may be null)
    int t, int w, int l, int quad, int lm)
{
    float hval[16];
    int urow = quad * 4 + (lm & 3);       // batch row this lane owns in epilogue
    int usub = lm >> 2;                   // unit sub-index within wave slice
    #pragma unroll
    for (int nc = 0; nc < 16; nc++) {
        // ---- stage Ws = Wg rows [nc*64, nc*64+64) : coalesced, bulk-issued ----
        const short* src = Wg + (size_t)(nc * 64) * 512;
        #pragma unroll 4
        for (int it = 0; it < 16; it++) {
            int idx = it * 256 + t;
            int row = idx >> 6, col = (idx & 63) * 8;
            *(uint4*)&s.Ws[row][col] = *(const uint4*)(src + row * 512 + col);
        }
        __syncthreads();
        // ---- MFMA: 16 k-steps as 2 chains ----
        f32x4 aA = {}, aB = {};
        #pragma unroll
        for (int ks = 0; ks < 8; ks++) {
            int kA = ks * 32 + quad * 8;
            int kB = kA + 256;
            short8 afA = *(const short8*)&X[lm][kA];
            short8 wfA = *(const short8*)&s.Ws[w * 16 + lm][kA];
            aA = __builtin_amdgcn_mfma_f32_16x16x32_bf16(afA, wfA, aA, 0, 0, 0);
            short8 afB = *(const short8*)&X[lm][kB];
            short8 wfB = *(const short8*)&s.Ws[w * 16 + lm][kB];
            aB = __builtin_amdgcn_mfma_f32_16x16x32_bf16(afB, wfB, aB, 0, 0, 0);
        }
        __syncthreads();   // all waves done with this Ws chunk (and X reads for it)
        // ---- per-chunk epilogue: 4x4 transpose via wave-private LDS, LSTM ----
        float bval = bg[nc * 64 + w * 16 + lm];
        #pragma unroll
        for (int r = 0; r < 4; r++)
            s.gSv[w][quad * 4 + r][lm] = aA[r] + aB[r] + bval;
        float4 g4 = *(const float4*)&s.gSv[w][urow][usub * 4];
        float si = 1.f / (1.f + __expf(-g4.x));
        float sf = 1.f / (1.f + __expf(-g4.y));
        float tg = 2.f / (1.f + __expf(-2.f * g4.z)) - 1.f;
        float so = 1.f / (1.f + __expf(-g4.w));
        float cn = sf * creg[nc] + si * tg;
        creg[nc] = cn;
        hval[nc] = so * (2.f / (1.f + __expf(-2.f * cn)) - 1.f);
    }
    // all X reads complete (sync inside last chunk) -> safe to write h now
    #pragma unroll
    for (int nc = 0; nc < 16; nc++) {
        short hb = f2b(hval[nc]);
        int u = nc * 16 + w * 4 + usub;
        D1[urow][o1 + u] = hb;
        if (D2) D2[urow][o2 + u] = hb;
    }
    __syncthreads();   // h visible to all waves
}

__global__ __launch_bounds__(256, 1) void decode_k(DecArgs a)
{
    __shared__ DecShared s;
    int t = threadIdx.x, w = t >> 6, l = t & 63, quad = l >> 4, lm = l & 15;
    int b0 = blockIdx.x * ROWS;

    // zero X0/X1; stage WaH for the whole kernel
    for (int i = t; i < ROWS * XP; i += 256) { (&s.X0[0][0])[i] = 0; (&s.X1[0][0])[i] = 0; }
    for (int i = t; i < 2560; i += 256) {
        int row = i >> 5, col = (i & 31) * 8;
        *(uint4*)&s.WaHs[row][col] = *(const uint4*)(a.WaHB + (size_t)row * 256 + col);
    }
    float c0r[16], c1r[16];
    #pragma unroll
    for (int i = 0; i < 16; i++) { c0r[i] = 0.f; c1r[i] = 0.f; }
    __syncthreads();

    for (int tt = 0; tt < T_; tt++) {
        // ---- attention scores: aw = h1_prev @ WaH^T + awE (16x80 via MFMA, LDS weights) ----
        {
            f32x4 acc0 = {}, acc1 = {};
            #pragma unroll
            for (int ks = 0; ks < 8; ks++) {
                int k0 = ks * 32 + quad * 8;
                short8 af = *(const short8*)&s.X1[lm][256 + k0];
                short8 wf0 = *(const short8*)&s.WaHs[w * 16 + lm][k0];
                acc0 = __builtin_amdgcn_mfma_f32_16x16x32_bf16(af, wf0, acc0, 0, 0, 0);
                if (w == 0) {
                    short8 wf1 = *(const short8*)&s.WaHs[64 + lm][k0];
                    acc1 = __builtin_amdgcn_mfma_f32_16x16x32_bf16(af, wf1, acc1, 0, 0, 0);
                }
            }
            const float* awEt = a.awE + ((size_t)tt * B_ + b0) * 80;
            #pragma unroll
            for (int r = 0; r < 4; r++) {
                int row = quad * 4 + r;
                s.awS[row][w * 16 + lm] = acc0[r] + awEt[(size_t)row * 80 + w * 16 + lm];
                if (w == 0)
                    s.awS[row][64 + lm] = acc1[r] + awEt[(size_t)row * 80 + 64 + lm];
            }
        }
        __syncthreads();
        // ---- softmax over 80 (wave w: rows 4w..4w+3; quad-group of 16 lanes per row) ----
        {
            int row = w * 4 + quad;
            float v[5];
            float mx = -1e30f;
            #pragma unroll
            for (int j = 0; j < 5; j++) { v[j] = s.awS[row][lm + 16 * j]; mx = fmaxf(mx, v[j]); }
            #pragma unroll
            for (int d = 1; d < 16; d <<= 1) mx = fmaxf(mx, __shfl_xor(mx, d));
            float sum = 0.f;
            #pragma unroll
            for (int j = 0; j < 5; j++) { v[j] = __expf(v[j] - mx); sum += v[j]; }
            #pragma unroll
            for (int d = 1; d < 16; d <<= 1) sum += __shfl_xor(sum, d);
            float inv = 1.f / sum;
            #pragma unroll
            for (int j = 0; j < 5; j++) s.apS[row][lm + 16 * j] = v[j] * inv;
        }
        // ---- apply + comb: comb = relu(sum_l ap[l]*encW[b,l,:] + combE) -> X0[:,0:256] ----
        {
            #pragma unroll
            for (int r_ = 0; r_ < 4; r_++) {
                int row = w * 4 + r_;
                int b = b0 + row;
                const short* ep = a.encW + ((size_t)b * 80) * 256 + l * 4;
                float o0 = 0.f, o1 = 0.f, o2 = 0.f, o3 = 0.f;
                #pragma unroll 8
                for (int ll = 0; ll < 80; ll++) {
                    float apv = s.apS[row][ll];
                    short4 ev = *(const short4*)(ep + (size_t)ll * 256);
                    o0 += apv * b2f(ev.x); o1 += apv * b2f(ev.y);
                    o2 += apv * b2f(ev.z); o3 += apv * b2f(ev.w);
                }
                float4 cE = *(const float4*)(a.combE + ((size_t)tt * B_ + b) * 256 + l * 4);
                short4 ov;
                ov.x = f2b(fmaxf(o0 + cE.x, 0.f));
                ov.y = f2b(fmaxf(o1 + cE.y, 0.f));
                ov.z = f2b(fmaxf(o2 + cE.z, 0.f));
                ov.w = f2b(fmaxf(o3 + cE.w, 0.f));
                *(short4*)&s.X0[row][l * 4] = ov;
            }
        }
        __syncthreads();
        // ---- layer 0: X0 -> h0 (to X1[:,0:256] for layer1, X0[:,256:] for next step) ----
        layer_lstm(s, s.X0, a.Wg0, a.bg0, c0r, s.X1, 0, s.X0, 256, t, w, l, quad, lm);
        // ---- layer 1: X1 -> h1 (to X1[:,256:512] for next step) ----
        layer_lstm(s, s.X1, a.Wg1, a.bg1, c1r, s.X1, 256, (short(*)[XP])nullptr, 0,
                   t, w, l, quad, lm);
        // ---- coalesced copy h1 -> global H1all slot tt ----
        {
            short* g = a.H1all + ((size_t)tt * B_ + b0) * 256;
            #pragma unroll
            for (int it = 0; it < 2; it++) {
                int idx = it * 256 + t;
                int row = idx >> 5, col = (idx & 31) * 8;
                *(uint4*)(g + (size_t)row * 256 + col) = *(const uint4*)&s.X1[row][256 + col];
            }
        }
    }
}

// ---------------- batched out GEMM + fused log-softmax ----------------

__global__ __launch_bounds__(256) void out_k(
    const short* __restrict__ h1B,     // [T*B, 256] bf16
    const short* __restrict__ WoB,
    const float* __restrict__ b_out,
    float* __restrict__ outT)          // [T*B, 256]
{
    __shared__ alignas(16) short As[32][40];
    __shared__ alignas(16) short Ws[256][40];
    __shared__ float oS[32][260];
    int m0 = blockIdx.x * 32;
    int t = threadIdx.x, w = t >> 6, l = t & 63, quad = l >> 4, lm = l & 15;
    int wm = (w >> 1) * 16, wn = (w & 1) * 128;
    f32x4 acc[8] = {};
    for (int k0 = 0; k0 < 256; k0 += 32) {
        if (t < 128) {
            int rr = t >> 2, cc = (t & 3) * 8;
            *(uint4*)&As[rr][cc] = *(const uint4*)(h1B + (size_t)(m0 + rr) * 256 + k0 + cc);
        }
        for (int cch = t; cch < 1024; cch += 256) {
            int rr = cch >> 2, cc = (cch & 3) * 8;
            *(uint4*)&Ws[rr][cc] = *(const uint4*)(WoB + (size_t)rr * 256 + k0 + cc);
        }
        __syncthreads();
        short8 af = *(const short8*)&As[wm + lm][quad * 8];
        #pragma unroll
        for (int j = 0; j < 8; j++) {
            short8 wf = *(const short8*)&Ws[wn + j * 16 + lm][quad * 8];
            acc[j] = __builtin_amdgcn_mfma_f32_16x16x32_bf16(af, wf, acc[j], 0, 0, 0);
        }
        __syncthreads();
    }
    #pragma unroll
    for (int j = 0; j < 8; j++)
        #pragma unroll
        for (int r = 0; r < 4; r++)
            oS[wm + quad * 4 + r][wn + j * 16 + lm] = acc[j][r] + b_out[wn + j * 16 + lm];
    __syncthreads();
    int row = t >> 3, q = t & 7;
    float mx = -1e30f;
    for (int i = q * 32; i < q * 32 + 32; i++) mx = fmaxf(mx, oS[row][i]);
    mx = fmaxf(mx, __shfl_xor(mx, 1));
    mx = fmaxf(mx, __shfl_xor(mx, 2));
    mx = fmaxf(mx, __shfl_xor(mx, 4));
    float sum = 0.f;
    for (int i = q * 32; i < q * 32 + 32; i++) sum += __expf(oS[row][i] - mx);
    sum += __shfl_xor(sum, 1); sum += __shfl_xor(sum, 2); sum += __shfl_xor(sum, 4);
    float lg = mx + logf(sum);
    float* orow = outT + (size_t)(m0 + row) * 256;
    for (int i = q * 32; i < q * 32 + 32; i++) orow[i] = oS[row][i] - lg;
}

// ---------------- host ----------------

extern "C" void kernel_launch(void* const* d_in, const int* in_sizes, int n_in,
                              void* d_out, int out_size, void* d_ws, size_t ws_size,
                              hipStream_t stream) {
    const float* encF    = (const float*)d_in[0];
    const float* syms    = (const float*)d_in[1];
    const int*   tsi     = (const int*)d_in[2];
    const float* commonE = (const float*)d_in[3];
    const float* W_attn  = (const float*)d_in[4];
    const float* b_attn  = (const float*)d_in[5];
    const float* W_comb  = (const float*)d_in[6];
    const float* b_comb  = (const float*)d_in[7];
    const float* Wih0    = (const float*)d_in[8];
    const float* Whh0    = (const float*)d_in[9];
    const float* bih0    = (const float*)d_in[10];
    const float* bhh0    = (const float*)d_in[11];
    const float* Wih1    = (const float*)d_in[12];
    const float* Whh1    = (const float*)d_in[13];
    const float* bih1    = (const float*)d_in[14];
    const float* bhh1    = (const float*)d_in[15];
    const float* W_out   = (const float*)d_in[16];
    const float* b_out   = (const float*)d_in[17];
    float* out = (float*)d_out;

    char* base = (char*)d_ws;
    size_t off = 0;
    auto alloc = [&](size_t bytes) -> char* {
        char* p = base + off;
        off += (bytes + 255) & ~(size_t)255;
        return p;
    };
    short* H1all = (short*)alloc((size_t)T_ * B_ * D_ * 2);
    float* awE   = (float*)alloc((size_t)T_ * B_ * L_ * 4);
    float* combE = (float*)alloc((size_t)T_ * B_ * D_ * 4);
    short* embB  = (short*)alloc((size_t)T_ * B_ * D_ * 2);
    short* WaEB  = (short*)alloc((size_t)L_ * D_ * 2);
    short* WaHB  = (short*)alloc((size_t)L_ * D_ * 2);
    short* WcEB  = (short*)alloc((size_t)D_ * D_ * 2);
    short* WcAB  = (short*)alloc((size_t)D_ * E_ * 2);
    short* Wg0B  = (short*)alloc((size_t)1024 * 512 * 2);
    short* Wg1B  = (short*)alloc((size_t)1024 * 512 * 2);
    short* WoutB = (short*)alloc((size_t)D_ * E_ * 2);
    float* bg0   = (float*)alloc(1024 * 4);
    float* bg1   = (float*)alloc(1024 * 4);
    short* encB  = (short*)alloc((size_t)B_ * L_ * E_ * 2);
    short* encW  = (short*)alloc((size_t)B_ * L_ * D_ * 2);  // enc @ W_combA^T, bf16
    (void)ws_size; (void)in_sizes; (void)n_in; (void)out_size;

    // ---- init / precompute (off the serial path) ----
    f2b4_k<<<4096, 256, 0, stream>>>(encF, encB, (size_t)B_ * L_ * E_ / 4);
    f2b4_k<<<64, 256, 0, stream>>>(W_out, WoutB, (size_t)D_ * E_ / 4);
    split_k<<<(80 * 512) / 256, 256, 0, stream>>>(W_attn, WaEB, WaHB, 80);
    split_k<<<(256 * 512) / 256, 256, 0, stream>>>(W_comb, WcEB, WcAB, 256);
    gatesW_k<<<2048, 256, 0, stream>>>(Wih0, Whh0, bih0, bhh0, Wg0B, bg0);
    gatesW_k<<<2048, 256, 0, stream>>>(Wih1, Whh1, bih1, bhh1, Wg1B, bg1);
    embed_k<<<(T_ * B_ * D_) / 256, 256, 0, stream>>>(tsi, commonE, syms, embB);
    // awE[t,b,l] = emb @ WaE^T + b_attn
    gemm_k<<<dim3(320, 2), 256, 0, stream>>>(embB, 256, WaEB, nullptr, 0, b_attn, 0,
                                             awE, 80, nullptr, 0, 20480, 80, 256);
    // combE[t,b,d] = emb @ WcE^T + b_comb
    gemm_k<<<dim3(320, 4), 256, 0, stream>>>(embB, 256, WcEB, nullptr, 0, b_comb, 0,
                                             combE, 256, nullptr, 0, 20480, 256, 256);
    // encW[b,l,:] = enc[b,l,:] @ WcA^T
    gemm_k<<<dim3(1280, 4), 256, 0, stream>>>(encB, 256, WcAB, nullptr, 0, nullptr, 0,
                                              nullptr, 0, encW, 256, 81920, 256, 256);

    // ---- batch-local persistent decode: ONE plain launch, LDS-staged weights ----
    DecArgs da;
    da.H1all = H1all; da.WaHB = WaHB; da.awE = awE; da.encW = encW; da.combE = combE;
    da.Wg0 = Wg0B; da.bg0 = bg0;
    da.Wg1 = Wg1B; da.bg1 = bg1;
    decode_k<<<NBLK, 256, 0, stream>>>(da);

    // ---- batched output projection + log-softmax over all T*B rows ----
    out_k<<<640, 256, 0, stream>>>(H1all, WoutB, b_out, out);
}

// Round 5
// 3933.422 us; speedup vs baseline: 1.2777x; 1.2777x over previous
//
#include <hip/hip_runtime.h>

#define B_ 1024
#define L_ 80
#define E_ 256
#define D_ 256
#define T_ 20
#define NS_ 4
#define NSYM_ 100

#define ROWS 16      // batch rows per decode block
#define NBLK 64      // B_ / ROWS
#define XP 520       // padded LDS row stride (shorts) for [16][512] X buffers
#define WAP 264      // padded LDS row stride (shorts) for WaH

typedef __attribute__((ext_vector_type(8))) short short8;
typedef __attribute__((ext_vector_type(4))) float f32x4;
typedef __attribute__((ext_vector_type(2))) int i32x2;
typedef __attribute__((ext_vector_type(4))) unsigned u32x4;

__device__ inline short f2b(float f) {
    unsigned u = __float_as_uint(f);
    unsigned r = (u + 0x7fffu + ((u >> 16) & 1u)) >> 16;
    return (short)r;
}
__device__ inline float b2f(short s) {
    return __uint_as_float(((unsigned)(unsigned short)s) << 16);
}

// ---------------- init / conversion kernels ----------------

__global__ void f2b4_k(const float* __restrict__ src, short* __restrict__ dst, size_t n4) {
    size_t i = (size_t)blockIdx.x * blockDim.x + threadIdx.x;
    size_t stride = (size_t)gridDim.x * blockDim.x;
    for (; i < n4; i += stride) {
        float4 v = ((const float4*)src)[i];
        short4 o;
        o.x = f2b(v.x); o.y = f2b(v.y); o.z = f2b(v.z); o.w = f2b(v.w);
        ((short4*)dst)[i] = o;
    }
}

// split W [rows, 512] into two bf16 [rows, 256] halves
__global__ void split_k(const float* __restrict__ Wsrc, short* __restrict__ dstE,
                        short* __restrict__ dstH, int rows) {
    int id = blockIdx.x * 256 + threadIdx.x;
    if (id >= rows * 512) return;
    int rr = id >> 9, cc = id & 511;
    short v = f2b(Wsrc[id]);
    if (cc < 256) dstE[rr * 256 + cc] = v;
    else          dstH[rr * 256 + (cc - 256)] = v;
}

// build gate-interleaved [1024, 512] bf16 weights: row (4u+g) = [Wih[g*256+u,:] | Whh[g*256+u,:]]
__global__ void gatesW_k(const float* __restrict__ Wih, const float* __restrict__ Whh,
                         const float* __restrict__ bih, const float* __restrict__ bhh,
                         short* __restrict__ WgB, float* __restrict__ bg) {
    int id = blockIdx.x * 256 + threadIdx.x;   // < 524288
    int np = id >> 9, cc = id & 511;
    int u = np >> 2, g = np & 3;
    int srow = g * 256 + u;
    float v = (cc < 256) ? Wih[srow * 256 + cc] : Whh[srow * 256 + (cc - 256)];
    WgB[id] = f2b(v);
    if (id < 1024) {
        int u2 = id >> 2, g2 = id & 3;
        bg[id] = bih[g2 * 256 + u2] + bhh[g2 * 256 + u2];
    }
}

// embedding gather -> bf16 embB [T*B, D] with row r = t*B + b
__global__ void embed_k(const int* __restrict__ tsi, const float* __restrict__ common,
                        const float* __restrict__ syms, short* __restrict__ embB) {
    size_t id = (size_t)blockIdx.x * 256 + threadIdx.x;  // < T*B*D
    int d = (int)(id & 255);
    size_t r = id >> 8;
    int tt = (int)(r >> 10);      // B_ = 1024
    int b  = (int)(r & 1023);
    int idx = tsi[b * T_ + tt];
    float v;
    if (idx < NS_) {
        int i2 = idx < 0 ? 0 : idx;
        v = common[i2 * D_ + d];
    } else {
        int i2 = idx - NS_;
        if (i2 > NSYM_ - 1) i2 = NSYM_ - 1;
        v = syms[((size_t)b * NSYM_ + i2) * D_ + d];
    }
    embB[id] = f2b(v);
}

// ---------------- generic bf16 MFMA GEMM: C = act(A @ W^T + addend + bias) ----------------

__global__ __launch_bounds__(256) void gemm_k(
    const short* __restrict__ A, int lda,
    const short* __restrict__ W,
    const float* __restrict__ addend, int ldAdd,
    const float* __restrict__ bias,
    int act,
    float* __restrict__ outF, int ldoF,
    short* __restrict__ outB, int ldoB,
    int M, int N, int K)
{
    __shared__ alignas(16) short As[64][40];
    __shared__ alignas(16) short Ws[64][40];
    int m0 = blockIdx.x * 64, n0 = blockIdx.y * 64;
    int t = threadIdx.x;
    int w = t >> 6, l = t & 63, quad = l >> 4, lm = l & 15;
    int wm = (w >> 1) * 32, wn = (w & 1) * 32;
    f32x4 acc[2][2] = {};
    int rowL = t >> 2, c8 = (t & 3) * 8;
    for (int k0 = 0; k0 < K; k0 += 32) {
        uint4 av = *(const uint4*)(A + (size_t)(m0 + rowL) * lda + k0 + c8);
        uint4 wv = {0u, 0u, 0u, 0u};
        int wr = n0 + rowL;
        if (wr < N) wv = *(const uint4*)(W + (size_t)wr * K + k0 + c8);
        *(uint4*)&As[rowL][c8] = av;
        *(uint4*)&Ws[rowL][c8] = wv;
        __syncthreads();
        short8 af[2], wf[2];
        af[0] = *(const short8*)&As[wm + lm][quad * 8];
        af[1] = *(const short8*)&As[wm + 16 + lm][quad * 8];
        wf[0] = *(const short8*)&Ws[wn + lm][quad * 8];
        wf[1] = *(const short8*)&Ws[wn + 16 + lm][quad * 8];
        #pragma unroll
        for (int i = 0; i < 2; i++)
            #pragma unroll
            for (int j = 0; j < 2; j++)
                acc[i][j] = __builtin_amdgcn_mfma_f32_16x16x32_bf16(af[i], wf[j], acc[i][j], 0, 0, 0);
        __syncthreads();
    }
    #pragma unroll
    for (int i = 0; i < 2; i++)
        #pragma unroll
        for (int j = 0; j < 2; j++) {
            int col = n0 + wn + j * 16 + lm;
            if (col >= N) continue;
            float bval = bias ? bias[col] : 0.f;
            #pragma unroll
            for (int r = 0; r < 4; r++) {
                int row = m0 + wm + i * 16 + quad * 4 + r;
                float v = acc[i][j][r] + bval;
                if (addend) v += addend[(size_t)row * ldAdd + col];
                if (act == 1) v = fmaxf(v, 0.f);
                if (outF) outF[(size_t)row * ldoF + col] = v;
                if (outB) outB[(size_t)row * ldoB + col] = f2b(v);
            }
        }
}

// ---------------- batch-local persistent decode ----------------
// 64 blocks x 16 batch rows x 8 waves; all T steps in-kernel.
// Weights read direct global->VGPR (L2-hot, protected by nt streaming loads),
// register double-buffered across k-steps. No grid syncs, no LDS weight staging.

struct DecArgs {
    short* H1all;        // [T*B, 256] bf16; slot tt = h1 after step tt
    const short* WaHB;   // [80, 256] bf16
    const float* awE;    // [T*B, 80]  (includes b_attn)
    const short* encW;   // [B, 80, 256] bf16 = enc @ WcA^T
    const float* combE;  // [T*B, 256] (includes b_comb)
    const short* Wg0; const float* bg0;
    const short* Wg1; const float* bg1;
};

struct DecShared {
    alignas(16) short X0[ROWS][XP];       // [comb | h0_prev]
    alignas(16) short X1[ROWS][XP];       // [h0   | h1_prev]
    alignas(16) short WaHs[80][WAP];      // staged attention weights (whole kernel)
    float awS[ROWS][80];
    float apS[ROWS][80];
    alignas(16) float gSv[8][ROWS][20];   // per-wave 4x4-transpose staging
};

// gates GEMM (16 x 1024, K=512) + LSTM for this block's 16 rows.
// Wave w owns gate cols [128w, 128w+128) = units [32w, 32w+32).
__device__ inline void layer_lstm8(
    DecShared& s,
    const short (*X)[XP],            // [16][512] bf16 input = [x | h_prev] (LDS)
    const short* __restrict__ Wg,    // [1024][512] bf16 gate-interleaved (global, L2-hot)
    const float* __restrict__ bg,    // [1024]
    float* creg,                     // [8] per-lane cell state
    short (*D1)[XP], int o1,         // LDS h dest 1
    short (*D2)[XP], int o2,         // LDS h dest 2 (may be null)
    int w, int l, int quad, int lm)
{
    const short* bp[8];
    #pragma unroll
    for (int j = 0; j < 8; j++)
        bp[j] = Wg + (size_t)(w * 128 + j * 16 + lm) * 512 + quad * 8;
    short8 wfA[8], wfB[8];
    #pragma unroll
    for (int j = 0; j < 8; j++) wfA[j] = *(const short8*)(bp[j]);
    f32x4 acc[8] = {};
    #pragma unroll
    for (int ks = 0; ks < 16; ks++) {
        short8 af = *(const short8*)&X[lm][ks * 32 + quad * 8];
        if ((ks & 1) == 0) {
            if (ks < 15) {
                #pragma unroll
                for (int j = 0; j < 8; j++) wfB[j] = *(const short8*)(bp[j] + (ks + 1) * 32);
            }
            #pragma unroll
            for (int j = 0; j < 8; j++)
                acc[j] = __builtin_amdgcn_mfma_f32_16x16x32_bf16(af, wfA[j], acc[j], 0, 0, 0);
        } else {
            if (ks < 15) {
                #pragma unroll
                for (int j = 0; j < 8; j++) wfA[j] = *(const short8*)(bp[j] + (ks + 1) * 32);
            }
            #pragma unroll
            for (int j = 0; j < 8; j++)
                acc[j] = __builtin_amdgcn_mfma_f32_16x16x32_bf16(af, wfB[j], acc[j], 0, 0, 0);
        }
    }
    __syncthreads();   // all waves done reading X -> safe to overwrite h regions later
    // per-frag epilogue: 4x4 transpose via wave-private LDS (in-order per wave), LSTM
    float hval[8];
    int urow = quad * 4 + (lm & 3);       // batch row this lane owns
    int usub = lm >> 2;                   // unit sub-index within frag
    #pragma unroll
    for (int i = 0; i < 8; i++) {
        float bv = bg[w * 128 + i * 16 + lm];
        #pragma unroll
        for (int r = 0; r < 4; r++)
            s.gSv[w][quad * 4 + r][lm] = acc[i][r] + bv;
        float4 g4 = *(const float4*)&s.gSv[w][urow][usub * 4];
        float si = 1.f / (1.f + __expf(-g4.x));
        float sf = 1.f / (1.f + __expf(-g4.y));
        float tg = 2.f / (1.f + __expf(-2.f * g4.z)) - 1.f;
        float so = 1.f / (1.f + __expf(-g4.w));
        float cn = sf * creg[i] + si * tg;
        creg[i] = cn;
        hval[i] = so * (2.f / (1.f + __expf(-2.f * cn)) - 1.f);
    }
    #pragma unroll
    for (int i = 0; i < 8; i++) {
        short hb = f2b(hval[i]);
        int u = w * 32 + i * 4 + usub;
        D1[urow][o1 + u] = hb;
        if (D2) D2[urow][o2 + u] = hb;
    }
    __syncthreads();   // h visible to all waves
}

__global__ __launch_bounds__(512, 2) void decode_k(DecArgs a)
{
    __shared__ DecShared s;
    int t = threadIdx.x, w = t >> 6, l = t & 63, quad = l >> 4, lm = l & 15;
    int b0 = blockIdx.x * ROWS;

    // zero X0/X1; stage WaH for the whole kernel
    for (int i = t; i < ROWS * XP; i += 512) { (&s.X0[0][0])[i] = 0; (&s.X1[0][0])[i] = 0; }
    for (int i = t; i < 2560; i += 512) {
        int row = i >> 5, col = (i & 31) * 8;
        *(uint4*)&s.WaHs[row][col] = *(const uint4*)(a.WaHB + (size_t)row * 256 + col);
    }
    float c0r[8], c1r[8];
    #pragma unroll
    for (int i = 0; i < 8; i++) { c0r[i] = 0.f; c1r[i] = 0.f; }
    __syncthreads();

    for (int tt = 0; tt < T_; tt++) {
        // ---- attention scores: aw = h1_prev @ WaH^T + awE (16x80 via MFMA, LDS weights) ----
        if (w < 5) {
            f32x4 acc0 = {};
            #pragma unroll
            for (int ks = 0; ks < 8; ks++) {
                int k0 = ks * 32 + quad * 8;
                short8 af = *(const short8*)&s.X1[lm][256 + k0];
                short8 wf0 = *(const short8*)&s.WaHs[w * 16 + lm][k0];
                acc0 = __builtin_amdgcn_mfma_f32_16x16x32_bf16(af, wf0, acc0, 0, 0, 0);
            }
            const float* awEt = a.awE + ((size_t)tt * B_ + b0) * 80;
            #pragma unroll
            for (int r = 0; r < 4; r++) {
                int row = quad * 4 + r;
                float ae = __builtin_nontemporal_load(awEt + (size_t)row * 80 + w * 16 + lm);
                s.awS[row][w * 16 + lm] = acc0[r] + ae;
            }
        }
        __syncthreads();
        // ---- softmax over 80 (wave w: rows 2w, 2w+1; two quad-pairs duplicate per row) ----
        {
            int row = w * 2 + (quad >> 1);
            float v[5];
            float mx = -1e30f;
            #pragma unroll
            for (int j = 0; j < 5; j++) { v[j] = s.awS[row][lm + 16 * j]; mx = fmaxf(mx, v[j]); }
            #pragma unroll
            for (int d = 1; d < 16; d <<= 1) mx = fmaxf(mx, __shfl_xor(mx, d));
            float sum = 0.f;
            #pragma unroll
            for (int j = 0; j < 5; j++) { v[j] = __expf(v[j] - mx); sum += v[j]; }
            #pragma unroll
            for (int d = 1; d < 16; d <<= 1) sum += __shfl_xor(sum, d);
            float inv = 1.f / sum;
            #pragma unroll
            for (int j = 0; j < 5; j++) s.apS[row][lm + 16 * j] = v[j] * inv;
        }
        // ---- apply + comb: comb = relu(sum_l ap[l]*encW[b,l,:] + combE) -> X0[:,0:256] ----
        {
            #pragma unroll
            for (int r_ = 0; r_ < 2; r_++) {
                int row = w * 2 + r_;
                int b = b0 + row;
                const i32x2* ep = (const i32x2*)(a.encW + ((size_t)b * 80) * 256 + l * 4);
                float o0 = 0.f, o1 = 0.f, o2 = 0.f, o3 = 0.f;
                #pragma unroll 8
                for (int ll = 0; ll < 80; ll++) {
                    float apv = s.apS[row][ll];
                    i32x2 ev2 = __builtin_nontemporal_load(ep + (size_t)ll * 64);
                    short4 ev = *(short4*)&ev2;
                    o0 += apv * b2f(ev.x); o1 += apv * b2f(ev.y);
                    o2 += apv * b2f(ev.z); o3 += apv * b2f(ev.w);
                }
                f32x4 cE = __builtin_nontemporal_load(
                    (const f32x4*)(a.combE + ((size_t)tt * B_ + b) * 256 + l * 4));
                short4 ov;
                ov.x = f2b(fmaxf(o0 + cE[0], 0.f));
                ov.y = f2b(fmaxf(o1 + cE[1], 0.f));
                ov.z = f2b(fmaxf(o2 + cE[2], 0.f));
                ov.w = f2b(fmaxf(o3 + cE[3], 0.f));
                *(short4*)&s.X0[row][l * 4] = ov;
            }
        }
        __syncthreads();
        // ---- layer 0: X0 -> h0 (to X1[:,0:256] for layer1, X0[:,256:] for next step) ----
        layer_lstm8(s, s.X0, a.Wg0, a.bg0, c0r, s.X1, 0, s.X0, 256, w, l, quad, lm);
        // ---- layer 1: X1 -> h1 (to X1[:,256:512] for next step) ----
        layer_lstm8(s, s.X1, a.Wg1, a.bg1, c1r, s.X1, 256, (short(*)[XP])nullptr, 0,
                    w, l, quad, lm);
        // ---- coalesced nt copy h1 -> global H1all slot tt ----
        {
            short* g = a.H1all + ((size_t)tt * B_ + b0) * 256;
            int row = t >> 5, col = (t & 31) * 8;
            u32x4 v = *(const u32x4*)&s.X1[row][256 + col];
            __builtin_nontemporal_store(v, (u32x4*)(g + (size_t)row * 256 + col));
        }
    }
}

// ---------------- batched out GEMM + fused log-softmax ----------------

__global__ __launch_bounds__(256) void out_k(
    const short* __restrict__ h1B,     // [T*B, 256] bf16
    const short* __restrict__ WoB,
    const float* __restrict__ b_out,
    float* __restrict__ outT)          // [T*B, 256]
{
    __shared__ alignas(16) short As[32][40];
    __shared__ alignas(16) short Ws[256][40];
    __shared__ float oS[32][260];
    int m0 = blockIdx.x * 32;
    int t = threadIdx.x, w = t >> 6, l = t & 63, quad = l >> 4, lm = l & 15;
    int wm = (w >> 1) * 16, wn = (w & 1) * 128;
    f32x4 acc[8] = {};
    for (int k0 = 0; k0 < 256; k0 += 32) {
        if (t < 128) {
            int rr = t >> 2, cc = (t & 3) * 8;
            *(uint4*)&As[rr][cc] = *(const uint4*)(h1B + (size_t)(m0 + rr) * 256 + k0 + cc);
        }
        for (int cch = t; cch < 1024; cch += 256) {
            int rr = cch >> 2, cc = (cch & 3) * 8;
            *(uint4*)&Ws[rr][cc] = *(const uint4*)(WoB + (size_t)rr * 256 + k0 + cc);
        }
        __syncthreads();
        short8 af = *(const short8*)&As[wm + lm][quad * 8];
        #pragma unroll
        for (int j = 0; j < 8; j++) {
            short8 wf = *(const short8*)&Ws[wn + j * 16 + lm][quad * 8];
            acc[j] = __builtin_amdgcn_mfma_f32_16x16x32_bf16(af, wf, acc[j], 0, 0, 0);
        }
        __syncthreads();
    }
    #pragma unroll
    for (int j = 0; j < 8; j++)
        #pragma unroll
        for (int r = 0; r < 4; r++)
            oS[wm + quad * 4 + r][wn + j * 16 + lm] = acc[j][r] + b_out[wn + j * 16 + lm];
    __syncthreads();
    int row = t >> 3, q = t & 7;
    float mx = -1e30f;
    for (int i = q * 32; i < q * 32 + 32; i++) mx = fmaxf(mx, oS[row][i]);
    mx = fmaxf(mx, __shfl_xor(mx, 1));
    mx = fmaxf(mx, __shfl_xor(mx, 2));
    mx = fmaxf(mx, __shfl_xor(mx, 4));
    float sum = 0.f;
    for (int i = q * 32; i < q * 32 + 32; i++) sum += __expf(oS[row][i] - mx);
    sum += __shfl_xor(sum, 1); sum += __shfl_xor(sum, 2); sum += __shfl_xor(sum, 4);
    float lg = mx + logf(sum);
    float* orow = outT + (size_t)(m0 + row) * 256;
    for (int i = q * 32; i < q * 32 + 32; i++) orow[i] = oS[row][i] - lg;
}

// ---------------- host ----------------

extern "C" void kernel_launch(void* const* d_in, const int* in_sizes, int n_in,
                              void* d_out, int out_size, void* d_ws, size_t ws_size,
                              hipStream_t stream) {
    const float* encF    = (const float*)d_in[0];
    const float* syms    = (const float*)d_in[1];
    const int*   tsi     = (const int*)d_in[2];
    const float* commonE = (const float*)d_in[3];
    const float* W_attn  = (const float*)d_in[4];
    const float* b_attn  = (const float*)d_in[5];
    const float* W_comb  = (const float*)d_in[6];
    const float* b_comb  = (const float*)d_in[7];
    const float* Wih0    = (const float*)d_in[8];
    const float* Whh0    = (const float*)d_in[9];
    const float* bih0    = (const float*)d_in[10];
    const float* bhh0    = (const float*)d_in[11];
    const float* Wih1    = (const float*)d_in[12];
    const float* Whh1    = (const float*)d_in[13];
    const float* bih1    = (const float*)d_in[14];
    const float* bhh1    = (const float*)d_in[15];
    const float* W_out   = (const float*)d_in[16];
    const float* b_out   = (const float*)d_in[17];
    float* out = (float*)d_out;

    char* base = (char*)d_ws;
    size_t off = 0;
    auto alloc = [&](size_t bytes) -> char* {
        char* p = base + off;
        off += (bytes + 255) & ~(size_t)255;
        return p;
    };
    short* H1all = (short*)alloc((size_t)T_ * B_ * D_ * 2);
    float* awE   = (float*)alloc((size_t)T_ * B_ * L_ * 4);
    float* combE = (float*)alloc((size_t)T_ * B_ * D_ * 4);
    short* embB  = (short*)alloc((size_t)T_ * B_ * D_ * 2);
    short* WaEB  = (short*)alloc((size_t)L_ * D_ * 2);
    short* WaHB  = (short*)alloc((size_t)L_ * D_ * 2);
    short* WcEB  = (short*)alloc((size_t)D_ * D_ * 2);
    short* WcAB  = (short*)alloc((size_t)D_ * E_ * 2);
    short* Wg0B  = (short*)alloc((size_t)1024 * 512 * 2);
    short* Wg1B  = (short*)alloc((size_t)1024 * 512 * 2);
    short* WoutB = (short*)alloc((size_t)D_ * E_ * 2);
    float* bg0   = (float*)alloc(1024 * 4);
    float* bg1   = (float*)alloc(1024 * 4);
    short* encB  = (short*)alloc((size_t)B_ * L_ * E_ * 2);
    short* encW  = (short*)alloc((size_t)B_ * L_ * D_ * 2);  // enc @ W_combA^T, bf16
    (void)ws_size; (void)in_sizes; (void)n_in; (void)out_size;

    // ---- init / precompute (off the serial path) ----
    f2b4_k<<<4096, 256, 0, stream>>>(encF, encB, (size_t)B_ * L_ * E_ / 4);
    f2b4_k<<<64, 256, 0, stream>>>(W_out, WoutB, (size_t)D_ * E_ / 4);
    split_k<<<(80 * 512) / 256, 256, 0, stream>>>(W_attn, WaEB, WaHB, 80);
    split_k<<<(256 * 512) / 256, 256, 0, stream>>>(W_comb, WcEB, WcAB, 256);
    gatesW_k<<<2048, 256, 0, stream>>>(Wih0, Whh0, bih0, bhh0, Wg0B, bg0);
    gatesW_k<<<2048, 256, 0, stream>>>(Wih1, Whh1, bih1, bhh1, Wg1B, bg1);
    embed_k<<<(T_ * B_ * D_) / 256, 256, 0, stream>>>(tsi, commonE, syms, embB);
    // awE[t,b,l] = emb @ WaE^T + b_attn
    gemm_k<<<dim3(320, 2), 256, 0, stream>>>(embB, 256, WaEB, nullptr, 0, b_attn, 0,
                                             awE, 80, nullptr, 0, 20480, 80, 256);
    // combE[t,b,d] = emb @ WcE^T + b_comb
    gemm_k<<<dim3(320, 4), 256, 0, stream>>>(embB, 256, WcEB, nullptr, 0, b_comb, 0,
                                             combE, 256, nullptr, 0, 20480, 256, 256);
    // encW[b,l,:] = enc[b,l,:] @ WcA^T
    gemm_k<<<dim3(1280, 4), 256, 0, stream>>>(encB, 256, WcAB, nullptr, 0, nullptr, 0,
                                              nullptr, 0, encW, 256, 81920, 256, 256);

    // ---- batch-local persistent decode: ONE plain launch ----
    DecArgs da;
    da.H1all = H1all; da.WaHB = WaHB; da.awE = awE; da.encW = encW; da.combE = combE;
    da.Wg0 = Wg0B; da.bg0 = bg0;
    da.Wg1 = Wg1B; da.bg1 = bg1;
    decode_k<<<NBLK, 512, 0, stream>>>(da);

    // ---- batched output projection + log-softmax over all T*B rows ----
    out_k<<<640, 256, 0, stream>>>(H1all, WoutB, b_out, out);
}